// Round 7
// baseline (189.062 us; speedup 1.0000x reference)
//
#include <hip/hip_runtime.h>
#include <cfloat>
#include <stdint.h>

#define B_   16
#define N_   2048
#define KK   10          // window = K+1
#define H_   128

#define RANK_BLOCKS (B_ * 32)                  // 512: 64-elem segments, 256 thr
#define WEFF_OUT    (H_ * KK * 2 + H_)         // 2688 outputs
#define WEFF_BLOCKS ((WEFF_OUT * 4) / 256)     // 42 (4 lanes/output, exact)

__device__ inline uint32_t f32_ordered(float f) {
    uint32_t u = __float_as_uint(f);
    return (u & 0x80000000u) ? ~u : (u | 0x80000000u);
}

// ---- setup (unchanged, ~6us): rank-by-count sort; unique keys ->
// exact permutation, output bitwise-identical to the original bitonic.
__global__ __launch_bounds__(256) void setup_kernel(
    const float* __restrict__ x,
    const float* __restrict__ Wconv, const float* __restrict__ bconv,
    const float* __restrict__ b1,    const float* __restrict__ W2,
    const float* __restrict__ b2,
    float4* __restrict__ xsorted,    // [B][N] (px,py,sm,orig_idx_bits)
    float*  __restrict__ weff,       // [H*20]
    float*  __restrict__ btot)       // [H]
{
#pragma clang fp contract(off)
    __shared__ __align__(16) uint64_t sk[N_];   // 16 KB
    __shared__ int pcnt[4 * 64];
    const int tid = threadIdx.x;

    if (blockIdx.x >= RANK_BLOCKS) {
        const int g = (blockIdx.x - RANK_BLOCKS) * 256 + tid;
        const int o = g >> 2, q = g & 3;
        float acc = 0.f;
        if (o < H_ * KK * 2) {
            const int e = o / 20, r = o % 20, k = r >> 1, c = r & 1;
            const float* w2p = W2 + e * H_ + q * 32;
            const float* wcp = Wconv + (q * 32) * (2 * KK) + c * KK + k;
#pragma unroll 8
            for (int h = 0; h < 32; ++h)
                acc += w2p[h] * wcp[h * (2 * KK)];
        } else {
            const int e = o - H_ * KK * 2;
            const float* w2p = W2 + e * H_ + q * 32;
            const float* bcp = bconv + q * 32;
#pragma unroll 8
            for (int h = 0; h < 32; ++h) acc += w2p[h] * bcp[h];
        }
        acc += __shfl_xor(acc, 1, 64);
        acc += __shfl_xor(acc, 2, 64);
        if (q == 0) {
            if (o < H_ * KK * 2) weff[o] = acc;
            else {
                const int e = o - H_ * KK * 2;
                btot[e] = acc + b1[e] + b2[e];
            }
        }
        return;
    }

    const int b  = blockIdx.x >> 5;
    const int sg = blockIdx.x & 31;
    const float2* xb = (const float2*)(x + (size_t)b * N_ * 2);

    for (int i = tid; i < N_; i += 256)
        sk[i] = ((uint64_t)f32_ordered(xb[i].x) << 32) | (uint32_t)i;
    __syncthreads();

    const int el = tid & 63;
    const int pt = tid >> 6;
    const uint64_t kown = sk[sg * 64 + el];
    const ulonglong2* sk2 = (const ulonglong2*)sk + pt * 256;
    int cnt = 0;
#pragma unroll 2
    for (int j = 0; j < 256; j += 4) {
        ulonglong2 t0 = sk2[j + 0];
        ulonglong2 t1 = sk2[j + 1];
        ulonglong2 t2 = sk2[j + 2];
        ulonglong2 t3 = sk2[j + 3];
        cnt += (int)(t0.x < kown) + (int)(t0.y < kown)
             + (int)(t1.x < kown) + (int)(t1.y < kown)
             + (int)(t2.x < kown) + (int)(t2.y < kown)
             + (int)(t3.x < kown) + (int)(t3.y < kown);
    }
    pcnt[pt * 64 + el] = cnt;
    __syncthreads();

    if (tid < 64) {
        const int r = pcnt[tid] + pcnt[64 + tid] + pcnt[128 + tid] + pcnt[192 + tid];
        const int i = sg * 64 + tid;
        float2 p = xb[i];
        float sm = p.x * p.x + p.y * p.y;   // no FMA (np sum convention)
        xsorted[(size_t)b * N_ + r] =
            make_float4(p.x, p.y, sm, __uint_as_float((uint32_t)i));
    }
}

// ---- main kernel v7: WAVE-PER-QUERY. 512 threads = 8 waves per 64-query
// tile; each wave serves its 8 consecutive queries sequentially. Per query:
// lanes 0-31 scan a 32-block left of the window edge, lanes 32-63 right,
// expanding outward. The top-10 list is DISTRIBUTED across lanes 0..9
// (lane r = rank r): accept = one ballot per 64 candidates (no per-lane
// ladder); insert = readlane-broadcast + ballot-rank + shfl_up shift
// (~14 instrs, only per TRUE accept). Gate = lane 9's d2 = exact running
// 10th-best; next query's gate seeded by the triangle inequality
// (d10(q') <= (sqrt(d10(q)) + dist(q,q'))^2), so only query 0 floods.
// Keys, d2 FP sequence, and termination margin identical -> same selected
// set and order -> output bitwise identical to R6.
__global__ __launch_bounds__(512, 4) void knn_conv_kernel(
    const float4* __restrict__ xsorted,
    const float* __restrict__ W1,
    const float* __restrict__ weff,
    const float* __restrict__ btot,
    float* __restrict__ out)
{
#pragma clang fp contract(off)
    __shared__ float4 xs4[N_];           // 32 KB
    __shared__ float  wcoord[64 * 21];   //  5.25 KB

    const int tid  = threadIdx.x;
    const int w    = tid >> 6;        // wave 0..7
    const int lane = tid & 63;
    const int b    = blockIdx.x >> 5;
    const int tile = blockIdx.x & 31;

    const float4* xb = xsorted + (size_t)b * N_;
    for (int i = tid; i < N_; i += 512) xs4[i] = xb[i];
    __syncthreads();

    const uint64_t KINIT = (((uint64_t)0x7F7FFFFFu) << 32) | 0x3FFFFFu;

    float gate_seed = FLT_MAX;   // triangle-seeded gate for current query
    float pqx = 0.f, pqy = 0.f;  // previous query coords (for delta)
    float ps9 = FLT_MAX;         // previous query final d10

    for (int j = 0; j < 8; ++j) {
        const int p = tile * 64 + w * 8 + j;   // query's sorted position
        const float4 qv = xs4[p];              // uniform -> broadcast
        const float qx = qv.x, qy = qv.y, sqn = qv.z;

        // triangle-inequality gate seed from previous (adjacent) query
        float gate;
        if (j == 0) gate = FLT_MAX;
        else {
            float dx = qx - pqx, dy = qy - pqy;
            float dq2 = dx * dx + dy * dy;
            float t = sqrtf(ps9) + sqrtf(dq2);
            gate = __builtin_fmaf(t * t, 1.0005f, 1e-6f);  // conservative slack
        }

        uint64_t s_list = KINIT;               // lane r<10: rank-r key
        int  le = p, re = p;
        bool ld = false, rd = false;

        while (!ld || !rd) {
            // candidate per lane: lanes 0-31 left block, 32-63 right block
            const bool left = (lane < 32);
            const int  m    = left ? (le - 32 + lane) : (re + lane - 32);
            const bool sok  = left ? !ld : !rd;
            const bool valid = sok && (m >= 0) && (m < N_);
            const int  mc   = valid ? m : 0;
            float4 c4 = xs4[mc];
            float s  = sqn + c4.z;
            float pr = qx * c4.x;
            float dt = __builtin_fmaf(qy, c4.y, pr);
            float d2 = __builtin_fmaf(-2.0f, dt, s);
            float dc = d2 > 0.0f ? d2 : 0.0f;
            const bool acc = valid && (dc <= gate);

            unsigned long long mask = __ballot(acc);
            if (mask) {
                const uint32_t oi = __float_as_uint(c4.w);
                const uint64_t key = ((uint64_t)__float_as_uint(dc) << 32)
                                   | (oi << 11) | (uint32_t)mc;
                do {
                    const int i = (int)__builtin_ctzll(mask);
                    mask &= mask - 1;
                    const uint64_t v =
                        (uint64_t)__shfl((unsigned long long)key, i, 64);
                    // rank-insert into the distributed sorted-10
                    unsigned long long bl = __ballot(s_list < v);
                    const int pos = (int)__popcll(bl & 0x3FFull);
                    const uint64_t sp =
                        (uint64_t)__shfl_up((unsigned long long)s_list, 1, 64);
                    s_list = (lane == pos) ? v : ((lane > pos) ? sp : s_list);
                } while (mask);
            }

            // exact 10th-best (FLT_MAX while list not full)
            const uint64_t s9 =
                (uint64_t)__shfl((unsigned long long)s_list, 9, 64);
            const float s9d = __uint_as_float((uint32_t)(s9 >> 32));
            gate = fminf(gate, s9d);

            // advance window; per-side termination (monotone gaps)
            le -= 32; re += 32;
            if (!ld) {
                if (le <= 0) ld = true;
                else {
                    float gl = qx - xs4[le - 1].x;                 // >= 0
                    if (__builtin_fmaf(gl, gl, -4e-6f) > s9d) ld = true;
                }
            }
            if (!rd) {
                if (re >= N_) rd = true;
                else {
                    float gr = xs4[re].x - qx;                     // >= 0
                    if (__builtin_fmaf(gr, gr, -4e-6f) > s9d) rd = true;
                }
            }
        }

        // write this query's 10 coords (lane r = rank r, nearest -> k=9)
        if (lane < KK) {
            float4 c = xs4[(int)(s_list & 0x7FF)];
            const int qloc = w * 8 + j;
            wcoord[qloc * 21 + 2 * (KK - 1 - lane) + 0] = c.x;
            wcoord[qloc * 21 + 2 * (KK - 1 - lane) + 1] = c.y;
        }

        // carry seed info to the next (adjacent) query
        {
            const uint64_t s9 =
                (uint64_t)__shfl((unsigned long long)s_list, 9, 64);
            ps9 = __uint_as_float((uint32_t)(s9 >> 32));
            pqx = qx; pqy = qy;
        }
    }

    // hoist epilogue weights (latency overlaps the barrier)
    const int e = tid & 127;
    float we[20];
    {
        const float4* wp = (const float4*)(weff + e * 20);
#pragma unroll
        for (int rr = 0; rr < 5; ++rr) {
            float4 v = wp[rr];
            we[4 * rr + 0] = v.x; we[4 * rr + 1] = v.y;
            we[4 * rr + 2] = v.z; we[4 * rr + 3] = v.w;
        }
    }
    const float w1x = W1[e * 2 + 0];
    const float w1y = W1[e * 2 + 1];
    const float bt  = btot[e];
    __syncthreads();

    // epilogue: thread -> channel e; rows scattered to ORIGINAL indices
    // (128 consecutive floats per row, coalesced per wave-store).
    const int qb_ = tid >> 7;
    const size_t obase = (size_t)b * N_ * H_;
#pragma unroll
    for (int jj = 0; jj < 16; ++jj) {
        const int qq = qb_ + 4 * jj;
        float4 xq = xs4[tile * 64 + qq];
        uint32_t orig = __float_as_uint(xq.w);
        const float* wc = &wcoord[qq * 21];
        float acc = bt;
        acc += xq.x * w1x;
        acc += xq.y * w1y;
#pragma unroll
        for (int k = 0; k < KK; ++k) {
            acc += wc[2 * k + 0] * we[2 * k + 0];
            acc += wc[2 * k + 1] * we[2 * k + 1];
        }
        out[obase + (size_t)orig * H_ + e] = acc;
    }
}

extern "C" void kernel_launch(void* const* d_in, const int* in_sizes, int n_in,
                              void* d_out, int out_size, void* d_ws, size_t ws_size,
                              hipStream_t stream) {
    const float* x     = (const float*)d_in[0];
    const float* Wconv = (const float*)d_in[1];
    const float* bconv = (const float*)d_in[2];
    const float* W1    = (const float*)d_in[3];
    const float* b1    = (const float*)d_in[4];
    const float* W2    = (const float*)d_in[5];
    const float* b2    = (const float*)d_in[6];
    float* out  = (float*)d_out;
    float* weff = (float*)d_ws;                           // 2560 floats
    float* btot = weff + H_ * KK * 2;                     // 128 floats
    float4* xsorted = (float4*)((char*)d_ws + 16384);     // 16*2048*16B

    setup_kernel<<<dim3(RANK_BLOCKS + WEFF_BLOCKS), dim3(256), 0, stream>>>(
        x, Wconv, bconv, b1, W2, b2, xsorted, weff, btot);
    knn_conv_kernel<<<dim3(B_ * (N_ / 64)), dim3(512), 0, stream>>>(
        xsorted, W1, weff, btot, out);
}

// Round 9
// 143.583 us; speedup vs baseline: 1.3167x; 1.3167x over previous
//
#include <hip/hip_runtime.h>
#include <cfloat>
#include <stdint.h>

#define B_   16
#define N_   2048
#define KK   10          // window = K+1
#define H_   128
#define SUB  32          // chunk size
#define NCH  (N_ / SUB)  // 64 chunks

#define RANK_BLOCKS (B_ * 32)                  // 512: 64-elem segments, 256 thr
#define WEFF_OUT    (H_ * KK * 2 + H_)         // 2688 outputs
#define WEFF_BLOCKS ((WEFF_OUT * 4) / 256)     // 42 (4 lanes/output, exact)

__device__ inline uint32_t f32_ordered(float f) {
    uint32_t u = __float_as_uint(f);
    return (u & 0x80000000u) ? ~u : (u | 0x80000000u);
}

// ---- setup (unchanged, ~6us): rank-by-count sort; unique keys ->
// exact permutation, output bitwise-identical to the original bitonic.
__global__ __launch_bounds__(256) void setup_kernel(
    const float* __restrict__ x,
    const float* __restrict__ Wconv, const float* __restrict__ bconv,
    const float* __restrict__ b1,    const float* __restrict__ W2,
    const float* __restrict__ b2,
    float4* __restrict__ xsorted,    // [B][N] (px,py,sm,orig_idx_bits)
    float*  __restrict__ weff,       // [H*20]
    float*  __restrict__ btot)       // [H]
{
#pragma clang fp contract(off)
    __shared__ __align__(16) uint64_t sk[N_];   // 16 KB
    __shared__ int pcnt[4 * 64];
    const int tid = threadIdx.x;

    if (blockIdx.x >= RANK_BLOCKS) {
        const int g = (blockIdx.x - RANK_BLOCKS) * 256 + tid;
        const int o = g >> 2, q = g & 3;
        float acc = 0.f;
        if (o < H_ * KK * 2) {
            const int e = o / 20, r = o % 20, k = r >> 1, c = r & 1;
            const float* w2p = W2 + e * H_ + q * 32;
            const float* wcp = Wconv + (q * 32) * (2 * KK) + c * KK + k;
#pragma unroll 8
            for (int h = 0; h < 32; ++h)
                acc += w2p[h] * wcp[h * (2 * KK)];
        } else {
            const int e = o - H_ * KK * 2;
            const float* w2p = W2 + e * H_ + q * 32;
            const float* bcp = bconv + q * 32;
#pragma unroll 8
            for (int h = 0; h < 32; ++h) acc += w2p[h] * bcp[h];
        }
        acc += __shfl_xor(acc, 1, 64);
        acc += __shfl_xor(acc, 2, 64);
        if (q == 0) {
            if (o < H_ * KK * 2) weff[o] = acc;
            else {
                const int e = o - H_ * KK * 2;
                btot[e] = acc + b1[e] + b2[e];
            }
        }
        return;
    }

    const int b  = blockIdx.x >> 5;
    const int sg = blockIdx.x & 31;
    const float2* xb = (const float2*)(x + (size_t)b * N_ * 2);

    for (int i = tid; i < N_; i += 256)
        sk[i] = ((uint64_t)f32_ordered(xb[i].x) << 32) | (uint32_t)i;
    __syncthreads();

    const int el = tid & 63;
    const int pt = tid >> 6;
    const uint64_t kown = sk[sg * 64 + el];
    const ulonglong2* sk2 = (const ulonglong2*)sk + pt * 256;
    int cnt = 0;
#pragma unroll 2
    for (int j = 0; j < 256; j += 4) {
        ulonglong2 t0 = sk2[j + 0];
        ulonglong2 t1 = sk2[j + 1];
        ulonglong2 t2 = sk2[j + 2];
        ulonglong2 t3 = sk2[j + 3];
        cnt += (int)(t0.x < kown) + (int)(t0.y < kown)
             + (int)(t1.x < kown) + (int)(t1.y < kown)
             + (int)(t2.x < kown) + (int)(t2.y < kown)
             + (int)(t3.x < kown) + (int)(t3.y < kown);
    }
    pcnt[pt * 64 + el] = cnt;
    __syncthreads();

    if (tid < 64) {
        const int r = pcnt[tid] + pcnt[64 + tid] + pcnt[128 + tid] + pcnt[192 + tid];
        const int i = sg * 64 + tid;
        float2 p = xb[i];
        float sm = p.x * p.x + p.y * p.y;   // no FMA (np sum convention)
        xsorted[(size_t)b * N_ + r] =
            make_float4(p.x, p.y, sm, __uint_as_float((uint32_t)i));
    }
}

// ---- main kernel v8: R6's query-partitioned waves (wave = 8 consecutive
// queries; lane = query qm x sub-lane r covering 4 strided positions/chunk)
// + TIGHT BOUNDS. R6's failure mode: sub-lane 10th-of-12 min-of-8 bound was
// so loose that expansion scanned ~30 chunks with near-every-slot insert
// ladders (any-of-64-lanes accept => ladder). v8 adds:
//  (1) exact post-phase-1 bound: non-destructive merge of the 8 sub-lane
//      sorted-10s -> the query's EXACT current 10th-best (valid upper bound
//      on the final d10; any union-top-10 element is in its sub-lane's list).
//  (2) refresh bound max_group(hk[1]): each sub-lane's 2 smallest are
//      <= its hk[1], so >=16 union elements <= max -> union 10th <= max.
// Gates only become tighter-but-valid -> identical selected sets -> output
// bitwise identical to R6.
__global__ __launch_bounds__(512, 4) void knn_conv_kernel(
    const float4* __restrict__ xsorted,
    const float* __restrict__ W1,
    const float* __restrict__ weff,
    const float* __restrict__ btot,
    float* __restrict__ out)
{
#pragma clang fp contract(off)
    __shared__ float4 xs4[N_];           // 32 KB
    __shared__ float  wcoord[64 * 21];   //  5.25 KB

    const int tid  = threadIdx.x;
    const int w    = tid >> 6;        // wave 0..7
    const int r    = tid & 7;         // sub-lane: candidate slice
    const int qm   = tid >> 3;        // query within tile (0..63)
    const int b    = blockIdx.x >> 5;
    const int tile = blockIdx.x & 31;

    const float4* xb = xsorted + (size_t)b * N_;
    for (int i = tid; i < N_; i += 512) xs4[i] = xb[i];
    __syncthreads();

    const float4 qv = xs4[tile * 64 + qm];
    const float  qx = qv.x, qy = qv.y, sqn = qv.z;
    const int    gfirst = tile * 64 + w * 8;      // wave's query group
    const float  qa  = xs4[gfirst].x;             // group x-range (uniform)
    const float  qbx = xs4[gfirst + 7].x;

    // sorted-10 of u64 keys: (d2_bits<<32)|(orig_idx<<11)|sorted_pos.
    const uint64_t KINIT = (((uint64_t)0x7F7FFFFFu) << 32) | 0x3FFFFFu;
    uint64_t hk[KK];
#pragma unroll
    for (int j = 0; j < KK; ++j) hk[j] = KINIT;
    float h9d  = FLT_MAX;   // 10th-best of own candidate subset
    float shb  = FLT_MAX;   // per-query shared bound (monotone nonincreasing)
    float gate = FLT_MAX;   // fminf(h9d, shb)

    auto insert = [&](float dc, float cw, int m) {
        uint32_t oi = __float_as_uint(cw);
        uint64_t key = ((uint64_t)__float_as_uint(dc) << 32)
                     | (oi << 11) | (uint32_t)m;
        if (key < hk[KK - 1]) {
#pragma unroll
            for (int j = KK - 1; j >= 1; --j) {
                bool cj  = key < hk[j];
                bool cjm = key < hk[j - 1];
                hk[j] = cj ? (cjm ? hk[j - 1] : key) : hk[j];
            }
            hk[0] = (key < hk[0]) ? key : hk[0];
        }
        h9d  = __uint_as_float((uint32_t)(hk[KK - 1] >> 32));
        gate = fminf(h9d, shb);
    };

    // sub-lane r scans positions mc+r, +8, +16, +24 (per-lane addresses;
    // 8 distinct float4 lines x 8-way broadcast = conflict-free).
    auto scan_chunk = [&](int mc) {
        const int m0 = mc + r;
        float4 c0 = xs4[m0 + 0];
        float4 c1 = xs4[m0 + 8];
        float4 c2 = xs4[m0 + 16];
        float4 c3 = xs4[m0 + 24];
        float dc0, dc1, dc2, dc3;
        { float s = sqn + c0.z; float pr = qx * c0.x;
          float dt = __builtin_fmaf(qy, c0.y, pr);
          float d2 = __builtin_fmaf(-2.0f, dt, s); dc0 = d2 > 0.0f ? d2 : 0.0f; }
        { float s = sqn + c1.z; float pr = qx * c1.x;
          float dt = __builtin_fmaf(qy, c1.y, pr);
          float d2 = __builtin_fmaf(-2.0f, dt, s); dc1 = d2 > 0.0f ? d2 : 0.0f; }
        { float s = sqn + c2.z; float pr = qx * c2.x;
          float dt = __builtin_fmaf(qy, c2.y, pr);
          float d2 = __builtin_fmaf(-2.0f, dt, s); dc2 = d2 > 0.0f ? d2 : 0.0f; }
        { float s = sqn + c3.z; float pr = qx * c3.x;
          float dt = __builtin_fmaf(qy, c3.y, pr);
          float d2 = __builtin_fmaf(-2.0f, dt, s); dc3 = d2 > 0.0f ? d2 : 0.0f; }
        if (dc0 <= gate) insert(dc0, c0.w, m0 + 0);
        if (dc1 <= gate) insert(dc1, c1.w, m0 + 8);
        if (dc2 <= gate) insert(dc2, c2.w, m0 + 16);
        if (dc3 <= gate) insert(dc3, c3.w, m0 + 24);
    };

    // bounds refresh: per-query bound = min(min_group(h9d), max_group(hk1)),
    // folded monotonically into shb; returns wave-max over the 8 queries.
    auto bounds = [&]() {
        float gb = h9d;
        gb = fminf(gb, __shfl_xor(gb, 1, 64));
        gb = fminf(gb, __shfl_xor(gb, 2, 64));
        gb = fminf(gb, __shfl_xor(gb, 4, 64));
        float h1 = __uint_as_float((uint32_t)(hk[1] >> 32));
        h1 = fmaxf(h1, __shfl_xor(h1, 1, 64));
        h1 = fmaxf(h1, __shfl_xor(h1, 2, 64));
        h1 = fmaxf(h1, __shfl_xor(h1, 4, 64));
        shb  = fminf(shb, fminf(gb, h1));
        gate = fminf(h9d, shb);
        float wm = shb;
        wm = fmaxf(wm, __shfl_xor(wm, 8,  64));
        wm = fmaxf(wm, __shfl_xor(wm, 16, 64));
        wm = fmaxf(wm, __shfl_xor(wm, 32, 64));
        return wm;   // max over the wave's 8 queries of their bounds
    };

    // phase 1: home chunk trio (12 candidates/lane >= 10 -> lists full).
    const int home = tile * 2 + (w >> 2);
    int c0s = home - 1;
    if (c0s < 0) c0s = 0;
    if (c0s > NCH - 3) c0s = NCH - 3;
    scan_chunk((c0s + 0) * SUB);
    scan_chunk((c0s + 1) * SUB);
    scan_chunk((c0s + 2) * SUB);

    // EXACT current 10th-best of the 96-candidate union (non-destructive
    // 8-list merge over register copies). Every union-top-10 element is in
    // its own sub-lane's top-10, so 10 selections find exactly the union's
    // 10 smallest; the 10th's d2 is a valid (and tight) gate.
    {
        uint64_t tc[KK];
#pragma unroll
        for (int j = 0; j < KK; ++j) tc[j] = hk[j];
        uint64_t last = 0;
#pragma unroll
        for (int sel = 0; sel < KK; ++sel) {
            uint64_t v  = tc[0];
            uint64_t t1 = __shfl_xor((unsigned long long)v, 1, 64);
            uint64_t m1 = v  < t1 ? v  : t1;
            uint64_t t2 = __shfl_xor((unsigned long long)m1, 2, 64);
            uint64_t m2 = m1 < t2 ? m1 : t2;
            uint64_t t4 = __shfl_xor((unsigned long long)m2, 4, 64);
            uint64_t vm = m2 < t4 ? m2 : t4;
            if (v == vm) {
#pragma unroll
                for (int j = 0; j < KK - 1; ++j) tc[j] = tc[j + 1];
                tc[KK - 1] = 0xFFFFFFFFFFFFFFFFull;
            }
            last = vm;
        }
        shb  = __uint_as_float((uint32_t)(last >> 32));
        gate = fminf(h9d, shb);
    }

    // phase 2: two-pointer outward, step 1, both sides per bounds() refresh
    // (stale-wm on the right is conservative: bounds only shrink). Gaps are
    // monotone per side -> a failed skip test kills that side for good.
    int  cl = c0s - 1, cr = c0s + 3;
    bool la = (cl >= 0), ra = (cr <= NCH - 1);
    while (la || ra) {
        float wm = bounds();
        if (la) {
            float gl = qa - xs4[cl * SUB + SUB - 1].x;            // >= 0
            if (__builtin_fmaf(gl, gl, -4e-6f) > wm) la = false;  // margin >> f32 d2 err
            else { scan_chunk(cl * SUB); cl -= 1; la = (cl >= 0); }
        }
        if (ra) {
            float gr = xs4[cr * SUB].x - qbx;                     // >= 0
            if (__builtin_fmaf(gr, gr, -4e-6f) > wm) ra = false;
            else { scan_chunk(cr * SUB); cr += 1; ra = (cr <= NCH - 1); }
        }
    }

    // hoist epilogue weights (latency overlaps merge + barrier)
    const int e = tid & 127;
    float we[20];
    {
        const float4* wp = (const float4*)(weff + e * 20);
#pragma unroll
        for (int rr = 0; rr < 5; ++rr) {
            float4 v = wp[rr];
            we[4 * rr + 0] = v.x; we[4 * rr + 1] = v.y;
            we[4 * rr + 2] = v.z; we[4 * rr + 3] = v.w;
        }
    }
    const float w1x = W1[e * 2 + 0];
    const float w1y = W1[e * 2 + 1];
    const float bt  = btot[e];

    // register merge: 8 sub-lane lists per query live in lanes (qm, r) --
    // exactly merge-8's layout. Head = hk[0]; winner shift-registers.
    // Keys unique -> exactly one winner per selection; 96 real keys >= 10.
    {
#pragma unroll
        for (int sel = 0; sel < KK; ++sel) {
            uint64_t v  = hk[0];
            uint64_t t1 = __shfl_xor((unsigned long long)v, 1, 64);
            uint64_t m1 = v  < t1 ? v  : t1;
            uint64_t t2 = __shfl_xor((unsigned long long)m1, 2, 64);
            uint64_t m2 = m1 < t2 ? m1 : t2;
            uint64_t t4 = __shfl_xor((unsigned long long)m2, 4, 64);
            uint64_t vm = m2 < t4 ? m2 : t4;
            if (v == vm) {
#pragma unroll
                for (int j = 0; j < KK - 1; ++j) hk[j] = hk[j + 1];
                hk[KK - 1] = 0xFFFFFFFFFFFFFFFFull;
            }
            if (r == 0) {
                float4 c = xs4[(int)(vm & 0x7FF)];
                const int k = (KK - 1) - sel;          // flip: nearest -> k=9
                wcoord[qm * 21 + 2 * k + 0] = c.x;
                wcoord[qm * 21 + 2 * k + 1] = c.y;
            }
        }
    }
    __syncthreads();

    // epilogue: thread -> channel e; rows scattered to ORIGINAL indices
    // (128 consecutive floats per row, coalesced per wave-store).
    const int qb_ = tid >> 7;
    const size_t obase = (size_t)b * N_ * H_;
#pragma unroll
    for (int jj = 0; jj < 16; ++jj) {
        const int qq = qb_ + 4 * jj;
        float4 xq = xs4[tile * 64 + qq];
        uint32_t orig = __float_as_uint(xq.w);
        const float* wc = &wcoord[qq * 21];
        float acc = bt;
        acc += xq.x * w1x;
        acc += xq.y * w1y;
#pragma unroll
        for (int k = 0; k < KK; ++k) {
            acc += wc[2 * k + 0] * we[2 * k + 0];
            acc += wc[2 * k + 1] * we[2 * k + 1];
        }
        out[obase + (size_t)orig * H_ + e] = acc;
    }
}

extern "C" void kernel_launch(void* const* d_in, const int* in_sizes, int n_in,
                              void* d_out, int out_size, void* d_ws, size_t ws_size,
                              hipStream_t stream) {
    const float* x     = (const float*)d_in[0];
    const float* Wconv = (const float*)d_in[1];
    const float* bconv = (const float*)d_in[2];
    const float* W1    = (const float*)d_in[3];
    const float* b1    = (const float*)d_in[4];
    const float* W2    = (const float*)d_in[5];
    const float* b2    = (const float*)d_in[6];
    float* out  = (float*)d_out;
    float* weff = (float*)d_ws;                           // 2560 floats
    float* btot = weff + H_ * KK * 2;                     // 128 floats
    float4* xsorted = (float4*)((char*)d_ws + 16384);     // 16*2048*16B

    setup_kernel<<<dim3(RANK_BLOCKS + WEFF_BLOCKS), dim3(256), 0, stream>>>(
        x, Wconv, bconv, b1, W2, b2, xsorted, weff, btot);
    knn_conv_kernel<<<dim3(B_ * (N_ / 64)), dim3(512), 0, stream>>>(
        xsorted, W1, weff, btot, out);
}